// Round 13
// baseline (385.622 us; speedup 1.0000x reference)
//
#include <hip/hip_runtime.h>
#include <math.h>

#define NB   8
#define SS   1024
#define DD   512
#define HH   8
#define DKK  64
#define NEGF (-3.0e38f)

// LDS strides (elements)
#define QSTR 88    // halves; 176 B rows, 16B-aligned b128 A-frags
#define SSTR 257   // floats; conflict-free score writes/pulls
#define PSTR 280   // halves; 560 B rows, 16B-aligned b128 A-frags
#define WSTR 40    // gemm staging: 80 B rows, 16B-aligned b128 frags

typedef _Float16 half8 __attribute__((ext_vector_type(8)));
typedef float    f32x4 __attribute__((ext_vector_type(4)));

// ---------------------------------------------------------------------------
// MFMA GEMM #1 — R6 64x64 version (measured better than 128x128 at K=512:
// 111 vs 121 us for the pair). q -> fp16 [b,h,s,dk]; v -> fp16 [b,h,dk,s].
// ---------------------------------------------------------------------------
__global__ __launch_bounds__(256) void gemm_qv(
    const float* __restrict__ x,
    const float* __restrict__ Wk, const float* __restrict__ bk,
    const float* __restrict__ Wv, const float* __restrict__ bv,
    _Float16* __restrict__ q_ws, _Float16* __restrict__ vt_ws)
{
    __shared__ __align__(16) _Float16 Asm[64 * WSTR];
    __shared__ __align__(16) _Float16 Bsm[64 * WSTR];

    const int m0  = blockIdx.x * 64;
    const int n0c = blockIdx.y * 64;          // 0..1023
    const bool is_v = (n0c >= DD);
    const float* __restrict__ Wp = is_v ? Wv : Wk;
    const float* __restrict__ bp = is_v ? bv : bk;
    const int n0 = n0c & (DD - 1);

    const int tid  = threadIdx.x;
    const int w    = tid >> 6;
    const int lane = tid & 63;
    const int quad = lane >> 4;
    const int n    = lane & 15;
    const int wm   = w >> 1, wn = w & 1;

    const int srow = tid >> 2;          // 0..63
    const int sc8  = (tid & 3) * 8;     // 0,8,16,24

    f32x4 acc[2][2] = {{{0.f,0.f,0.f,0.f},{0.f,0.f,0.f,0.f}},
                       {{0.f,0.f,0.f,0.f},{0.f,0.f,0.f,0.f}}};

    for (int k0 = 0; k0 < DD; k0 += 32) {
        __syncthreads();
        {
            const float* src = &x[(size_t)(m0 + srow) * DD + k0 + sc8];
            float4 f0 = *(const float4*)&src[0];
            float4 f1 = *(const float4*)&src[4];
            half8 hv = {(_Float16)f0.x,(_Float16)f0.y,(_Float16)f0.z,(_Float16)f0.w,
                        (_Float16)f1.x,(_Float16)f1.y,(_Float16)f1.z,(_Float16)f1.w};
            *(half8*)&Asm[srow * WSTR + sc8] = hv;
        }
        {
            const float* src = &Wp[(size_t)(n0 + srow) * DD + k0 + sc8];
            float4 f0 = *(const float4*)&src[0];
            float4 f1 = *(const float4*)&src[4];
            half8 hv = {(_Float16)f0.x,(_Float16)f0.y,(_Float16)f0.z,(_Float16)f0.w,
                        (_Float16)f1.x,(_Float16)f1.y,(_Float16)f1.z,(_Float16)f1.w};
            *(half8*)&Bsm[srow * WSTR + sc8] = hv;
        }
        __syncthreads();
        half8 a0 = *(const half8*)&Asm[(wm*32 +  0 + n) * WSTR + quad*8];
        half8 a1 = *(const half8*)&Asm[(wm*32 + 16 + n) * WSTR + quad*8];
        half8 b0 = *(const half8*)&Bsm[(wn*32 +  0 + n) * WSTR + quad*8];
        half8 b1 = *(const half8*)&Bsm[(wn*32 + 16 + n) * WSTR + quad*8];
        acc[0][0] = __builtin_amdgcn_mfma_f32_16x16x32_f16(a0, b0, acc[0][0], 0,0,0);
        acc[0][1] = __builtin_amdgcn_mfma_f32_16x16x32_f16(a0, b1, acc[0][1], 0,0,0);
        acc[1][0] = __builtin_amdgcn_mfma_f32_16x16x32_f16(a1, b0, acc[1][0], 0,0,0);
        acc[1][1] = __builtin_amdgcn_mfma_f32_16x16x32_f16(a1, b1, acc[1][1], 0,0,0);
    }

    const int h = n0 >> 6;   // head (n0 is 64-aligned)
    #pragma unroll
    for (int tm = 0; tm < 2; ++tm) {
        #pragma unroll
        for (int tn = 0; tn < 2; ++tn) {
            const int dk = wn*32 + tn*16 + n;        // 0..63 within head
            const float bias = bp[n0 + dk];
            const int gbase = m0 + wm*32 + tm*16 + quad*4;   // 4 consecutive rows
            const int bidx  = gbase >> 10;
            const int sr    = gbase & (SS - 1);
            if (!is_v) {
                #pragma unroll
                for (int reg = 0; reg < 4; ++reg)
                    q_ws[((size_t)(bidx * HH + h) * SS + sr + reg) * DKK + dk] =
                        (_Float16)(acc[tm][tn][reg] + bias);
            } else {
                _Float16 h4[4];
                #pragma unroll
                for (int reg = 0; reg < 4; ++reg)
                    h4[reg] = (_Float16)(acc[tm][tn][reg] + bias);
                *(uint2*)&vt_ws[((size_t)(bidx * HH + h) * DKK + dk) * SS + sr] =
                    *(uint2*)h4;
            }
        }
    }
}

// ---------------------------------------------------------------------------
// MFMA GEMM #2 — R6 64x64 version: out = attn @ Wo^T + bo (out fp32)
// ---------------------------------------------------------------------------
__global__ __launch_bounds__(256) void gemm_out(
    const float* __restrict__ A,
    const float* __restrict__ Wo, const float* __restrict__ bo,
    float* __restrict__ out)
{
    __shared__ __align__(16) _Float16 Asm[64 * WSTR];
    __shared__ __align__(16) _Float16 Bsm[64 * WSTR];

    const int m0 = blockIdx.x * 64;
    const int n0 = blockIdx.y * 64;

    const int tid  = threadIdx.x;
    const int w    = tid >> 6;
    const int lane = tid & 63;
    const int quad = lane >> 4;
    const int n    = lane & 15;
    const int wm   = w >> 1, wn = w & 1;

    const int srow = tid >> 2;
    const int sc8  = (tid & 3) * 8;

    f32x4 acc[2][2] = {{{0.f,0.f,0.f,0.f},{0.f,0.f,0.f,0.f}},
                       {{0.f,0.f,0.f,0.f},{0.f,0.f,0.f,0.f}}};

    for (int k0 = 0; k0 < DD; k0 += 32) {
        __syncthreads();
        {
            const float* src = &A[(size_t)(m0 + srow) * DD + k0 + sc8];
            float4 f0 = *(const float4*)&src[0];
            float4 f1 = *(const float4*)&src[4];
            half8 hv = {(_Float16)f0.x,(_Float16)f0.y,(_Float16)f0.z,(_Float16)f0.w,
                        (_Float16)f1.x,(_Float16)f1.y,(_Float16)f1.z,(_Float16)f1.w};
            *(half8*)&Asm[srow * WSTR + sc8] = hv;
        }
        {
            const float* src = &Wo[(size_t)(n0 + srow) * DD + k0 + sc8];
            float4 f0 = *(const float4*)&src[0];
            float4 f1 = *(const float4*)&src[4];
            half8 hv = {(_Float16)f0.x,(_Float16)f0.y,(_Float16)f0.z,(_Float16)f0.w,
                        (_Float16)f1.x,(_Float16)f1.y,(_Float16)f1.z,(_Float16)f1.w};
            *(half8*)&Bsm[srow * WSTR + sc8] = hv;
        }
        __syncthreads();
        half8 a0 = *(const half8*)&Asm[(wm*32 +  0 + n) * WSTR + quad*8];
        half8 a1 = *(const half8*)&Asm[(wm*32 + 16 + n) * WSTR + quad*8];
        half8 b0 = *(const half8*)&Bsm[(wn*32 +  0 + n) * WSTR + quad*8];
        half8 b1 = *(const half8*)&Bsm[(wn*32 + 16 + n) * WSTR + quad*8];
        acc[0][0] = __builtin_amdgcn_mfma_f32_16x16x32_f16(a0, b0, acc[0][0], 0,0,0);
        acc[0][1] = __builtin_amdgcn_mfma_f32_16x16x32_f16(a0, b1, acc[0][1], 0,0,0);
        acc[1][0] = __builtin_amdgcn_mfma_f32_16x16x32_f16(a1, b0, acc[1][0], 0,0,0);
        acc[1][1] = __builtin_amdgcn_mfma_f32_16x16x32_f16(a1, b1, acc[1][1], 0,0,0);
    }

    #pragma unroll
    for (int tm = 0; tm < 2; ++tm) {
        #pragma unroll
        for (int tn = 0; tn < 2; ++tn) {
            const int col  = n0 + wn*32 + tn*16 + n;
            const float bias = bo[col];
            #pragma unroll
            for (int reg = 0; reg < 4; ++reg) {
                const int grow = m0 + wm*32 + tm*16 + quad*4 + reg;
                out[(size_t)grow * DD + col] = acc[tm][tn][reg] + bias;
            }
        }
    }
}

// ---------------------------------------------------------------------------
// MFMA attention, R13: 8-wave blocks (512 thr, 8 rows) for occupancy
// (1.3 -> 4 blocks/CU; barrier-bound kernel needs independent work to hide
// barrier stalls). MFMA tiles stay 16-row; upper 8 rows computed & discarded
// (utT loads / score writes / output stores masked to kept rows; p_lds rows
// 8..15 zeroed once). Per-row math identical to the verified R6 kernel.
// ---------------------------------------------------------------------------
__global__ __launch_bounds__(512) void attn_mfma(
    const _Float16* __restrict__ q,   // [B,H,S,DK] fp16 (K = Q)
    const _Float16* __restrict__ vt,  // [B,H,DK,S] fp16 (V transposed)
    const float* __restrict__ utT,    // [B,S,S]
    const float* __restrict__ gammas, // [H]
    float* __restrict__ attn)         // [B,S,H,DK] fp32
{
    __shared__ __align__(16) float    s_lds[2 * 8 * SSTR];   // 16448 B (8 kept rows)
    __shared__ __align__(16) _Float16 p_lds[2 * 16 * PSTR];  // 17920 B (16 rows, 8..15 zero)
    __shared__ __align__(16) _Float16 q_lds[16 * QSTR];      // 2816 B

    const int tid  = threadIdx.x;
    const int w    = tid >> 6;        // 0..7
    const int lane = tid & 63;
    const int quad = lane >> 4;
    const int n    = lane & 15;
    const int bh   = blockIdx.y;
    const int b    = bh >> 3;
    const int h    = bh & 7;
    const int r0   = blockIdx.x * 8;

    const _Float16* __restrict__ kq  = q  + (size_t)bh * SS * DKK;
    const _Float16* __restrict__ vtp = vt + (size_t)bh * DKK * SS;

    const int nchunk = (r0 + 8 + 255) >> 8;   // 1..4, block-uniform
    const int nt     = nchunk * 4;

    // ---- stage Q rows r0..r0+15 (clamped; MFMA A needs 16 rows) ----
    if (tid < 256) {
        const int row = tid >> 4;
        const int c   = tid & 15;
        int gr = r0 + row; if (gr > SS - 1) gr = SS - 1;
        *(uint2*)&q_lds[row * QSTR + c * 4] =
            *(const uint2*)&kq[(size_t)gr * DKK + c * 4];
    }
    // ---- zero p_lds rows 8..15 in both buffers, once (A-frag upper half) ----
    #pragma unroll
    for (int bufi = 0; bufi < 2; ++bufi) {
        _Float16* prow = &p_lds[bufi * 16 * PSTR + (8 + w) * PSTR];
        for (int c = lane; c * 2 < PSTR; c += 64)
            *(unsigned*)&prow[c * 2] = 0u;
    }
    __syncthreads();

    float sreg[16];
    #pragma unroll
    for (int t2 = 0; t2 < 16; ++t2) sreg[t2] = NEGF;

    // ================= Phase 1: scores via MFMA (K frags from global) =======
    #pragma unroll
    for (int c0 = 0; c0 < 4; ++c0) {
        if (c0 < nchunk) {
            const int j0  = c0 * 256;
            const int buf = (c0 & 1) * 8 * SSTR;
            #pragma unroll
            for (int rep = 0; rep < 2; ++rep) {
                const int jt    = w + rep * 8;          // 0..15
                const int jbase = j0 + jt * 16;
                if (jbase <= r0 + 7) {                  // tile causally needed
                    const _Float16* krow = &kq[(size_t)(jbase + n) * DKK];
                    half8 b0 = *(const half8*)&krow[quad * 8];
                    half8 b1 = *(const half8*)&krow[32 + quad * 8];
                    half8 a0 = *(const half8*)&q_lds[n * QSTR + quad * 8];
                    half8 a1 = *(const half8*)&q_lds[n * QSTR + 32 + quad * 8];
                    f32x4 d = {0.f, 0.f, 0.f, 0.f};
                    d = __builtin_amdgcn_mfma_f32_16x16x32_f16(a0, b0, d, 0, 0, 0);
                    d = __builtin_amdgcn_mfma_f32_16x16x32_f16(a1, b1, d, 0, 0, 0);
                    const int j = jbase + n;
                    if (quad < 2) {                     // kept rows r0..r0+7
                        #pragma unroll
                        for (int reg = 0; reg < 4; ++reg) {
                            const int i = r0 + quad * 4 + reg;
                            float val = NEGF;
                            if (j <= i)
                                val = d[reg] * 0.125f * utT[((size_t)b * SS + i) * SS + j];
                            s_lds[buf + (quad * 4 + reg) * SSTR + jt * 16 + n] = val;
                        }
                    }
                } else {
                    if (quad < 2) {
                        #pragma unroll
                        for (int reg = 0; reg < 4; ++reg)
                            s_lds[buf + (quad * 4 + reg) * SSTR + jt * 16 + n] = NEGF;
                    }
                }
            }
            __syncthreads();
            #pragma unroll
            for (int ttl = 0; ttl < 4; ++ttl)
                sreg[c0 * 4 + ttl] = s_lds[buf + w * SSTR + ttl * 64 + lane];
        }
    }

    // ================= Phase 2: softmax / scan / decay (row = r0+w) =========
    const int i_row = r0 + w;

    float m1 = NEGF;
    #pragma unroll
    for (int t2 = 0; t2 < 16; ++t2) if (t2 < nt) m1 = fmaxf(m1, sreg[t2]);
    #pragma unroll
    for (int o = 32; o >= 1; o >>= 1) m1 = fmaxf(m1, __shfl_xor(m1, o));

    float ee[16];
    float z1 = 0.f;
    #pragma unroll
    for (int t2 = 0; t2 < 16; ++t2) {
        float e = 0.f;
        if (t2 < nt) {
            const int j = t2 * 64 + lane;
            if (j <= i_row) e = __expf(sreg[t2] - m1);
        }
        ee[t2] = e;
        z1 += e;
    }
    #pragma unroll
    for (int o = 32; o >= 1; o >>= 1) z1 += __shfl_xor(z1, o);
    const float inv_z1 = 1.0f / z1;

    const float g     = gammas[h];
    const float gamma = -log1pf(__expf(g));   // -softplus

    float carry = 0.f;
    float m2 = NEGF;
    #pragma unroll
    for (int t2 = 0; t2 < 16; ++t2) {
        if (t2 < nt) {
            float xv = ee[t2];
            #pragma unroll
            for (int o = 1; o < 64; o <<= 1) {
                float y = __shfl_up(xv, (unsigned)o);
                if (lane >= o) xv += y;
            }
            const float tile_tot = __shfl(xv, 63);
            const float csum = (carry + xv) * inv_z1;
            carry += tile_tot;

            const int j = t2 * 64 + lane;
            const float pe = (float)(i_row - j);
            const float dd = fmaxf((1.0f - csum) * pe, 0.0f);
            float te = __expf(sqrtf(dd) * gamma);
            te = fminf(fmaxf(te, 1e-5f), 1e5f);
            const float nsv = (j <= i_row) ? sreg[t2] * te : NEGF;
            ee[t2] = nsv;
            m2 = fmaxf(m2, nsv);
        }
    }
    #pragma unroll
    for (int o = 32; o >= 1; o >>= 1) m2 = fmaxf(m2, __shfl_xor(m2, o));

    float z2 = 0.f;
    #pragma unroll
    for (int t2 = 0; t2 < 16; ++t2) {
        if (t2 < nt) {
            ee[t2] = __expf(ee[t2] - m2);
            z2 += ee[t2];
        }
    }
    #pragma unroll
    for (int o = 32; o >= 1; o >>= 1) z2 += __shfl_xor(z2, o);
    const float inv_z2 = 1.0f / z2;
    #pragma unroll
    for (int t2 = 0; t2 < 16; ++t2) if (t2 < nt) ee[t2] *= inv_z2;

    // ================= Phase 3: PV via MFMA (V^T frags from global) =========
    f32x4 oacc = {0.f, 0.f, 0.f, 0.f};
    #pragma unroll
    for (int c0 = 0; c0 < 4; ++c0) {
        if (c0 < nchunk) {
            const int j0 = c0 * 256;
            const int pb = (c0 & 1) * 16 * PSTR;
            #pragma unroll
            for (int ttl = 0; ttl < 4; ++ttl)
                p_lds[pb + w * PSTR + ttl * 64 + lane] = (_Float16)ee[c0 * 4 + ttl];
            __syncthreads();
            if (w < 4) {
                int nkt = (r0 + 8 - j0 + 31) >> 5;
                nkt = (nkt > 8) ? 8 : nkt;   // 1..8
                const _Float16* vrow = &vtp[(size_t)(w * 16 + n) * SS + j0];
                for (int kt = 0; kt < nkt; ++kt) {
                    half8 a  = *(const half8*)&p_lds[pb + n * PSTR + kt * 32 + quad * 8];
                    half8 bb = *(const half8*)&vrow[kt * 32 + quad * 8];
                    oacc = __builtin_amdgcn_mfma_f32_16x16x32_f16(a, bb, oacc, 0, 0, 0);
                }
            }
        }
    }

    if (w < 4 && quad < 2) {      // kept rows r0..r0+7, dslice = w
        #pragma unroll
        for (int reg = 0; reg < 4; ++reg) {
            const int i = r0 + quad * 4 + reg;
            attn[(((size_t)b * SS + i) * HH + h) * DKK + w * 16 + n] = oacc[reg];
        }
    }
}

// ---------------------------------------------------------------------------
extern "C" void kernel_launch(void* const* d_in, const int* in_sizes, int n_in,
                              void* d_out, int out_size, void* d_ws, size_t ws_size,
                              hipStream_t stream) {
    const float* x      = (const float*)d_in[0];
    const float* utT    = (const float*)d_in[1];
    const float* Wk     = (const float*)d_in[2];
    const float* bk     = (const float*)d_in[3];
    const float* Wv     = (const float*)d_in[4];
    const float* bv     = (const float*)d_in[5];
    const float* Wo     = (const float*)d_in[6];
    const float* bo     = (const float*)d_in[7];
    const float* gammas = (const float*)d_in[8];
    float* out = (float*)d_out;

    const size_t per = (size_t)NB * HH * SS * DKK;  // 4,194,304 elements
    _Float16* q_ws   = (_Float16*)d_ws;             // 8 MB, [b,h,s,dk]
    _Float16* vt_ws  = q_ws + per;                  // 8 MB, [b,h,dk,s]
    float*    attn_ws = (float*)(vt_ws + per);      // 16 MB

    dim3 g1(128, 16);
    gemm_qv<<<g1, dim3(256), 0, stream>>>(x, Wk, bk, Wv, bv, q_ws, vt_ws);

    dim3 g2(SS / 8, NB * HH);
    attn_mfma<<<g2, dim3(512), 0, stream>>>(q_ws, vt_ws, utT, gammas, attn_ws);

    dim3 g3(128, 8);
    gemm_out<<<g3, dim3(256), 0, stream>>>(attn_ws, Wo, bo, out);
}

// Round 14
// 338.740 us; speedup vs baseline: 1.1384x; 1.1384x over previous
//
#include <hip/hip_runtime.h>
#include <math.h>

#define NB   8
#define SS   1024
#define DD   512
#define HH   8
#define DKK  64
#define NEGF (-3.0e38f)

// LDS strides (elements)
#define QSTR 88    // halves; 176 B rows, 16B-aligned b128 A-frags
#define SSTR 257   // floats; conflict-free score writes/pulls
#define PSTR 280   // halves; 560 B rows, 16B-aligned b128 A-frags
#define WSTR 40    // gemm staging: 80 B rows, 16B-aligned b128 frags
#define TSTR 68    // gemm q-epilogue transpose buffer stride (halves)

typedef _Float16 half8 __attribute__((ext_vector_type(8)));
typedef float    f32x4 __attribute__((ext_vector_type(4)));

// ---------------------------------------------------------------------------
// MFMA GEMM #1 — R6 64x64 + R14 coalesced q-epilogue (LDS transpose ->
// uint4 stores; was 16 scattered 2B stores/thread). v path unchanged.
// ---------------------------------------------------------------------------
__global__ __launch_bounds__(256) void gemm_qv(
    const float* __restrict__ x,
    const float* __restrict__ Wk, const float* __restrict__ bk,
    const float* __restrict__ Wv, const float* __restrict__ bv,
    _Float16* __restrict__ q_ws, _Float16* __restrict__ vt_ws)
{
    __shared__ __align__(16) _Float16 Asm[64 * WSTR];
    __shared__ __align__(16) _Float16 Bsm[64 * WSTR];
    __shared__ __align__(16) _Float16 Tsm[64 * TSTR];   // 8704 B, epilogue only

    const int m0  = blockIdx.x * 64;
    const int n0c = blockIdx.y * 64;          // 0..1023
    const bool is_v = (n0c >= DD);
    const float* __restrict__ Wp = is_v ? Wv : Wk;
    const float* __restrict__ bp = is_v ? bv : bk;
    const int n0 = n0c & (DD - 1);

    const int tid  = threadIdx.x;
    const int w    = tid >> 6;
    const int lane = tid & 63;
    const int quad = lane >> 4;
    const int n    = lane & 15;
    const int wm   = w >> 1, wn = w & 1;

    const int srow = tid >> 2;          // 0..63
    const int sc8  = (tid & 3) * 8;     // 0,8,16,24

    f32x4 acc[2][2] = {{{0.f,0.f,0.f,0.f},{0.f,0.f,0.f,0.f}},
                       {{0.f,0.f,0.f,0.f},{0.f,0.f,0.f,0.f}}};

    for (int k0 = 0; k0 < DD; k0 += 32) {
        __syncthreads();
        {
            const float* src = &x[(size_t)(m0 + srow) * DD + k0 + sc8];
            float4 f0 = *(const float4*)&src[0];
            float4 f1 = *(const float4*)&src[4];
            half8 hv = {(_Float16)f0.x,(_Float16)f0.y,(_Float16)f0.z,(_Float16)f0.w,
                        (_Float16)f1.x,(_Float16)f1.y,(_Float16)f1.z,(_Float16)f1.w};
            *(half8*)&Asm[srow * WSTR + sc8] = hv;
        }
        {
            const float* src = &Wp[(size_t)(n0 + srow) * DD + k0 + sc8];
            float4 f0 = *(const float4*)&src[0];
            float4 f1 = *(const float4*)&src[4];
            half8 hv = {(_Float16)f0.x,(_Float16)f0.y,(_Float16)f0.z,(_Float16)f0.w,
                        (_Float16)f1.x,(_Float16)f1.y,(_Float16)f1.z,(_Float16)f1.w};
            *(half8*)&Bsm[srow * WSTR + sc8] = hv;
        }
        __syncthreads();
        half8 a0 = *(const half8*)&Asm[(wm*32 +  0 + n) * WSTR + quad*8];
        half8 a1 = *(const half8*)&Asm[(wm*32 + 16 + n) * WSTR + quad*8];
        half8 b0 = *(const half8*)&Bsm[(wn*32 +  0 + n) * WSTR + quad*8];
        half8 b1 = *(const half8*)&Bsm[(wn*32 + 16 + n) * WSTR + quad*8];
        acc[0][0] = __builtin_amdgcn_mfma_f32_16x16x32_f16(a0, b0, acc[0][0], 0,0,0);
        acc[0][1] = __builtin_amdgcn_mfma_f32_16x16x32_f16(a0, b1, acc[0][1], 0,0,0);
        acc[1][0] = __builtin_amdgcn_mfma_f32_16x16x32_f16(a1, b0, acc[1][0], 0,0,0);
        acc[1][1] = __builtin_amdgcn_mfma_f32_16x16x32_f16(a1, b1, acc[1][1], 0,0,0);
    }

    const int h = n0 >> 6;   // head (n0 is 64-aligned)
    if (!is_v) {
        // ---- q epilogue: C tile -> LDS (with bias) -> coalesced uint4 stores
        __syncthreads();     // all frag reads of Asm/Bsm done
        #pragma unroll
        for (int tm = 0; tm < 2; ++tm) {
            #pragma unroll
            for (int tn = 0; tn < 2; ++tn) {
                const int dk = wn*32 + tn*16 + n;
                const float bias = bp[n0 + dk];
                const int rbase = wm*32 + tm*16 + quad*4;
                #pragma unroll
                for (int reg = 0; reg < 4; ++reg)
                    Tsm[(rbase + reg) * TSTR + dk] =
                        (_Float16)(acc[tm][tn][reg] + bias);
            }
        }
        __syncthreads();
        {   // 64 rows x 64 dk: thread -> row=tid>>2, 16 halves at (tid&3)*16
            const int row = tid >> 2;
            const int c16 = (tid & 3) * 16;
            const int grow = m0 + row;
            const int bidx = grow >> 10;
            const int sr   = grow & (SS - 1);
            _Float16* dst = &q_ws[((size_t)(bidx * HH + h) * SS + sr) * DKK + c16];
            *(uint4*)&dst[0] = *(const uint4*)&Tsm[row * TSTR + c16];
            *(uint4*)&dst[8] = *(const uint4*)&Tsm[row * TSTR + c16 + 8];
        }
    } else {
        // ---- v epilogue (unchanged): transposed [b,h,dk,s], uint2 stores
        #pragma unroll
        for (int tm = 0; tm < 2; ++tm) {
            #pragma unroll
            for (int tn = 0; tn < 2; ++tn) {
                const int dk = wn*32 + tn*16 + n;
                const float bias = bp[n0 + dk];
                const int gbase = m0 + wm*32 + tm*16 + quad*4;
                const int bidx  = gbase >> 10;
                const int sr    = gbase & (SS - 1);
                _Float16 h4[4];
                #pragma unroll
                for (int reg = 0; reg < 4; ++reg)
                    h4[reg] = (_Float16)(acc[tm][tn][reg] + bias);
                *(uint2*)&vt_ws[((size_t)(bidx * HH + h) * DKK + dk) * SS + sr] =
                    *(uint2*)h4;
            }
        }
    }
}

// ---------------------------------------------------------------------------
// MFMA GEMM #2 — R6 64x64 version (unchanged): out = attn @ Wo^T + bo
// ---------------------------------------------------------------------------
__global__ __launch_bounds__(256) void gemm_out(
    const float* __restrict__ A,
    const float* __restrict__ Wo, const float* __restrict__ bo,
    float* __restrict__ out)
{
    __shared__ __align__(16) _Float16 Asm[64 * WSTR];
    __shared__ __align__(16) _Float16 Bsm[64 * WSTR];

    const int m0 = blockIdx.x * 64;
    const int n0 = blockIdx.y * 64;

    const int tid  = threadIdx.x;
    const int w    = tid >> 6;
    const int lane = tid & 63;
    const int quad = lane >> 4;
    const int n    = lane & 15;
    const int wm   = w >> 1, wn = w & 1;

    const int srow = tid >> 2;
    const int sc8  = (tid & 3) * 8;

    f32x4 acc[2][2] = {{{0.f,0.f,0.f,0.f},{0.f,0.f,0.f,0.f}},
                       {{0.f,0.f,0.f,0.f},{0.f,0.f,0.f,0.f}}};

    for (int k0 = 0; k0 < DD; k0 += 32) {
        __syncthreads();
        {
            const float* src = &A[(size_t)(m0 + srow) * DD + k0 + sc8];
            float4 f0 = *(const float4*)&src[0];
            float4 f1 = *(const float4*)&src[4];
            half8 hv = {(_Float16)f0.x,(_Float16)f0.y,(_Float16)f0.z,(_Float16)f0.w,
                        (_Float16)f1.x,(_Float16)f1.y,(_Float16)f1.z,(_Float16)f1.w};
            *(half8*)&Asm[srow * WSTR + sc8] = hv;
        }
        {
            const float* src = &Wo[(size_t)(n0 + srow) * DD + k0 + sc8];
            float4 f0 = *(const float4*)&src[0];
            float4 f1 = *(const float4*)&src[4];
            half8 hv = {(_Float16)f0.x,(_Float16)f0.y,(_Float16)f0.z,(_Float16)f0.w,
                        (_Float16)f1.x,(_Float16)f1.y,(_Float16)f1.z,(_Float16)f1.w};
            *(half8*)&Bsm[srow * WSTR + sc8] = hv;
        }
        __syncthreads();
        half8 a0 = *(const half8*)&Asm[(wm*32 +  0 + n) * WSTR + quad*8];
        half8 a1 = *(const half8*)&Asm[(wm*32 + 16 + n) * WSTR + quad*8];
        half8 b0 = *(const half8*)&Bsm[(wn*32 +  0 + n) * WSTR + quad*8];
        half8 b1 = *(const half8*)&Bsm[(wn*32 + 16 + n) * WSTR + quad*8];
        acc[0][0] = __builtin_amdgcn_mfma_f32_16x16x32_f16(a0, b0, acc[0][0], 0,0,0);
        acc[0][1] = __builtin_amdgcn_mfma_f32_16x16x32_f16(a0, b1, acc[0][1], 0,0,0);
        acc[1][0] = __builtin_amdgcn_mfma_f32_16x16x32_f16(a1, b0, acc[1][0], 0,0,0);
        acc[1][1] = __builtin_amdgcn_mfma_f32_16x16x32_f16(a1, b1, acc[1][1], 0,0,0);
    }

    #pragma unroll
    for (int tm = 0; tm < 2; ++tm) {
        #pragma unroll
        for (int tn = 0; tn < 2; ++tn) {
            const int col  = n0 + wn*32 + tn*16 + n;
            const float bias = bo[col];
            #pragma unroll
            for (int reg = 0; reg < 4; ++reg) {
                const int grow = m0 + wm*32 + tm*16 + quad*4 + reg;
                out[(size_t)grow * DD + col] = acc[tm][tn][reg] + bias;
            }
        }
    }
}

// ---------------------------------------------------------------------------
// MFMA attention — EXACT R6 kernel (227 µs, twice-reproduced). Known-toxic
// variants (do not retry): 16-wave PV + o_red (R7, +100 µs); utT fold into
// post-barrier pull + tmax (R10, +100 µs); 8-wave blocks (R13, +51 µs).
// ---------------------------------------------------------------------------
__global__ __launch_bounds__(1024) void attn_mfma(
    const _Float16* __restrict__ q,   // [B,H,S,DK] fp16 (K = Q)
    const _Float16* __restrict__ vt,  // [B,H,DK,S] fp16 (V transposed)
    const float* __restrict__ utT,    // [B,S,S]
    const float* __restrict__ gammas, // [H]
    float* __restrict__ attn)         // [B,S,H,DK] fp32
{
    __shared__ __align__(16) float    s_lds[2 * 16 * SSTR];  // 32896 B
    __shared__ __align__(16) _Float16 q_lds[16 * QSTR];      // 2816 B
    _Float16* p_lds = (_Float16*)s_lds;  // phase 3: 2 x 16 x PSTR halves (17920 B)

    const int tid  = threadIdx.x;
    const int w    = tid >> 6;
    const int lane = tid & 63;
    const int quad = lane >> 4;
    const int n    = lane & 15;
    const int bh   = blockIdx.y;
    const int b    = bh >> 3;
    const int h    = bh & 7;
    const int r0   = blockIdx.x * 16;

    const _Float16* __restrict__ kq  = q  + (size_t)bh * SS * DKK;
    const _Float16* __restrict__ vtp = vt + (size_t)bh * DKK * SS;

    const int nchunk = (r0 + 16 + 255) >> 8;   // 1..4, block-uniform
    const int nt     = nchunk * 4;

    // ---- stage Q rows r0..r0+15 (fp16 copy; reused by all 16 waves) ----
    if (tid < 256) {
        const int row = tid >> 4;
        const int c   = tid & 15;
        *(uint2*)&q_lds[row * QSTR + c * 4] =
            *(const uint2*)&kq[(size_t)(r0 + row) * DKK + c * 4];
    }
    __syncthreads();

    float sreg[16];
    #pragma unroll
    for (int t2 = 0; t2 < 16; ++t2) sreg[t2] = NEGF;

    // ================= Phase 1: scores via MFMA (K frags from global) =======
    #pragma unroll
    for (int c0 = 0; c0 < 4; ++c0) {
        if (c0 < nchunk) {
            const int j0  = c0 * 256;
            const int buf = (c0 & 1) * 16 * SSTR;
            const int jbase = j0 + w * 16;
            if (jbase <= r0 + 15) {
                const _Float16* krow = &kq[(size_t)(jbase + n) * DKK];
                half8 b0 = *(const half8*)&krow[quad * 8];
                half8 b1 = *(const half8*)&krow[32 + quad * 8];
                half8 a0 = *(const half8*)&q_lds[n * QSTR + quad * 8];
                half8 a1 = *(const half8*)&q_lds[n * QSTR + 32 + quad * 8];
                f32x4 d = {0.f, 0.f, 0.f, 0.f};
                d = __builtin_amdgcn_mfma_f32_16x16x32_f16(a0, b0, d, 0, 0, 0);
                d = __builtin_amdgcn_mfma_f32_16x16x32_f16(a1, b1, d, 0, 0, 0);
                const int j = jbase + n;
                #pragma unroll
                for (int reg = 0; reg < 4; ++reg) {
                    const int i = r0 + quad * 4 + reg;
                    float val = NEGF;
                    if (j <= i)
                        val = d[reg] * 0.125f * utT[((size_t)b * SS + i) * SS + j];
                    s_lds[buf + (quad * 4 + reg) * SSTR + w * 16 + n] = val;
                }
            } else {
                #pragma unroll
                for (int reg = 0; reg < 4; ++reg)
                    s_lds[buf + (quad * 4 + reg) * SSTR + w * 16 + n] = NEGF;
            }
            __syncthreads();
            #pragma unroll
            for (int ttl = 0; ttl < 4; ++ttl)
                sreg[c0 * 4 + ttl] = s_lds[buf + w * SSTR + ttl * 64 + lane];
        }
    }

    // ================= Phase 2: softmax / scan / decay (row = r0+w) =========
    const int i_row = r0 + w;

    float m1 = NEGF;
    #pragma unroll
    for (int t2 = 0; t2 < 16; ++t2) if (t2 < nt) m1 = fmaxf(m1, sreg[t2]);
    #pragma unroll
    for (int o = 32; o >= 1; o >>= 1) m1 = fmaxf(m1, __shfl_xor(m1, o));

    float ee[16];
    float z1 = 0.f;
    #pragma unroll
    for (int t2 = 0; t2 < 16; ++t2) {
        float e = 0.f;
        if (t2 < nt) {
            const int j = t2 * 64 + lane;
            if (j <= i_row) e = __expf(sreg[t2] - m1);
        }
        ee[t2] = e;
        z1 += e;
    }
    #pragma unroll
    for (int o = 32; o >= 1; o >>= 1) z1 += __shfl_xor(z1, o);
    const float inv_z1 = 1.0f / z1;

    const float g     = gammas[h];
    const float gamma = -log1pf(__expf(g));   // -softplus

    float carry = 0.f;
    float m2 = NEGF;
    #pragma unroll
    for (int t2 = 0; t2 < 16; ++t2) {
        if (t2 < nt) {
            float xv = ee[t2];
            #pragma unroll
            for (int o = 1; o < 64; o <<= 1) {
                float y = __shfl_up(xv, (unsigned)o);
                if (lane >= o) xv += y;
            }
            const float tile_tot = __shfl(xv, 63);
            const float csum = (carry + xv) * inv_z1;
            carry += tile_tot;

            const int j = t2 * 64 + lane;
            const float pe = (float)(i_row - j);
            const float dd = fmaxf((1.0f - csum) * pe, 0.0f);
            float te = __expf(sqrtf(dd) * gamma);
            te = fminf(fmaxf(te, 1e-5f), 1e5f);
            const float nsv = (j <= i_row) ? sreg[t2] * te : NEGF;
            ee[t2] = nsv;
            m2 = fmaxf(m2, nsv);
        }
    }
    #pragma unroll
    for (int o = 32; o >= 1; o >>= 1) m2 = fmaxf(m2, __shfl_xor(m2, o));

    float z2 = 0.f;
    #pragma unroll
    for (int t2 = 0; t2 < 16; ++t2) {
        if (t2 < nt) {
            ee[t2] = __expf(ee[t2] - m2);
            z2 += ee[t2];
        }
    }
    #pragma unroll
    for (int o = 32; o >= 1; o >>= 1) z2 += __shfl_xor(z2, o);
    const float inv_z2 = 1.0f / z2;
    #pragma unroll
    for (int t2 = 0; t2 < 16; ++t2) if (t2 < nt) ee[t2] *= inv_z2;

    __syncthreads();   // phase-3 entry: all s_lds pulls done before p aliases

    // ================= Phase 3: PV via MFMA (V^T frags from global) =========
    f32x4 oacc = {0.f, 0.f, 0.f, 0.f};
    #pragma unroll
    for (int c0 = 0; c0 < 4; ++c0) {
        if (c0 < nchunk) {
            const int j0 = c0 * 256;
            const int pb = (c0 & 1) * 16 * PSTR;
            #pragma unroll
            for (int ttl = 0; ttl < 4; ++ttl)
                p_lds[pb + w * PSTR + ttl * 64 + lane] = (_Float16)ee[c0 * 4 + ttl];
            __syncthreads();
            if (w < 4) {
                int nkt = (r0 + 16 - j0 + 31) >> 5;
                nkt = (nkt > 8) ? 8 : nkt;   // 1..8
                const _Float16* vrow = &vtp[(size_t)(w * 16 + n) * SS + j0];
                for (int kt = 0; kt < nkt; ++kt) {
                    half8 a  = *(const half8*)&p_lds[pb + n * PSTR + kt * 32 + quad * 8];
                    half8 bb = *(const half8*)&vrow[kt * 32 + quad * 8];
                    oacc = __builtin_amdgcn_mfma_f32_16x16x32_f16(a, bb, oacc, 0, 0, 0);
                }
            }
        }
    }

    if (w < 4) {
        #pragma unroll
        for (int reg = 0; reg < 4; ++reg) {
            const int i = r0 + quad * 4 + reg;
            attn[(((size_t)b * SS + i) * HH + h) * DKK + w * 16 + n] = oacc[reg];
        }
    }
}

// ---------------------------------------------------------------------------
extern "C" void kernel_launch(void* const* d_in, const int* in_sizes, int n_in,
                              void* d_out, int out_size, void* d_ws, size_t ws_size,
                              hipStream_t stream) {
    const float* x      = (const float*)d_in[0];
    const float* utT    = (const float*)d_in[1];
    const float* Wk     = (const float*)d_in[2];
    const float* bk     = (const float*)d_in[3];
    const float* Wv     = (const float*)d_in[4];
    const float* bv     = (const float*)d_in[5];
    const float* Wo     = (const float*)d_in[6];
    const float* bo     = (const float*)d_in[7];
    const float* gammas = (const float*)d_in[8];
    float* out = (float*)d_out;

    const size_t per = (size_t)NB * HH * SS * DKK;  // 4,194,304 elements
    _Float16* q_ws   = (_Float16*)d_ws;             // 8 MB, [b,h,s,dk]
    _Float16* vt_ws  = q_ws + per;                  // 8 MB, [b,h,dk,s]
    float*    attn_ws = (float*)(vt_ws + per);      // 16 MB

    dim3 g1(128, 16);
    gemm_qv<<<g1, dim3(256), 0, stream>>>(x, Wk, bk, Wv, bv, q_ws, vt_ws);

    dim3 g2(SS / 16, NB * HH);
    attn_mfma<<<g2, dim3(1024), 0, stream>>>(q_ws, vt_ws, utT, gammas, attn_ws);

    dim3 g3(128, 8);
    gemm_out<<<g3, dim3(256), 0, stream>>>(attn_ws, Wo, bo, out);
}

// Round 15
// 330.117 us; speedup vs baseline: 1.1681x; 1.0261x over previous
//
#include <hip/hip_runtime.h>
#include <math.h>

#define NB   8
#define SS   1024
#define DD   512
#define HH   8
#define DKK  64
#define NEGF (-3.0e38f)

// LDS strides (elements)
#define QSTR 88    // halves; attn q tile
#define SSTR 257   // floats; attn score rows
#define PSTR 280   // halves; attn p rows
// gemm DMA slabs are PACKED (stride 32 halves) — global_load_lds forbids padding.

typedef _Float16 half8 __attribute__((ext_vector_type(8)));
typedef float    f32x4 __attribute__((ext_vector_type(4)));

// async 16B/lane global->LDS (wave-uniform LDS base + lane*16)
#define GLDS16(g, l) __builtin_amdgcn_global_load_lds( \
    (const __attribute__((address_space(1))) void*)(g), \
    (__attribute__((address_space(3))) void*)(l), 16, 0, 0)

// ---------------------------------------------------------------------------
// cvt: x, Wk, Wv, Wo (fp32) -> fp16 buffers. 8 elems/thread.
// ---------------------------------------------------------------------------
__global__ __launch_bounds__(256) void cvt_fp16(
    const float* __restrict__ x,  _Float16* __restrict__ xh,
    const float* __restrict__ wk, _Float16* __restrict__ wkh,
    const float* __restrict__ wv, _Float16* __restrict__ wvh,
    const float* __restrict__ wo, _Float16* __restrict__ woh)
{
    const size_t NX = (size_t)NB * SS * DD;   // 4194304
    const size_t NW = (size_t)DD * DD;        // 262144
    size_t f = ((size_t)blockIdx.x * 256 + threadIdx.x) * 8;
    const float* src; _Float16* dst; size_t off;
    if (f < NX)               { src = x;  dst = xh;  off = f; }
    else if (f < NX + NW)     { src = wk; dst = wkh; off = f - NX; }
    else if (f < NX + 2*NW)   { src = wv; dst = wvh; off = f - NX - 2*NW + NW; }
    else                      { src = wo; dst = woh; off = f - NX - 2*NW; }
    float4 f0 = *(const float4*)&src[off];
    float4 f1 = *(const float4*)&src[off + 4];
    half8 hv = {(_Float16)f0.x,(_Float16)f0.y,(_Float16)f0.z,(_Float16)f0.w,
                (_Float16)f1.x,(_Float16)f1.y,(_Float16)f1.z,(_Float16)f1.w};
    *(half8*)&dst[off] = hv;
}

// ---------------------------------------------------------------------------
// GEMM #1, m97-style: 128x128 tile, BK=32, global_load_lds staging.
// q = xh@Wk^T + bk -> fp16 [b,h,s,dk]; v = xh@Wv^T + bv -> fp16 [b,h,dk,s].
// ---------------------------------------------------------------------------
__global__ __launch_bounds__(256) void gemm_qv(
    const _Float16* __restrict__ xh,
    const _Float16* __restrict__ wkh, const float* __restrict__ bk,
    const _Float16* __restrict__ wvh, const float* __restrict__ bv,
    _Float16* __restrict__ q_ws, _Float16* __restrict__ vt_ws)
{
    __shared__ __align__(16) _Float16 Ah[128 * 32];   // 8192 B, packed
    __shared__ __align__(16) _Float16 Bh[128 * 32];

    const int m0  = blockIdx.x * 128;
    const int n0c = blockIdx.y * 128;
    const bool is_v = (n0c >= DD);
    const _Float16* __restrict__ Wp = is_v ? wvh : wkh;
    const float*    __restrict__ bp = is_v ? bv : bk;
    const int n0 = n0c & (DD - 1);

    const int tid  = threadIdx.x;
    const int w    = tid >> 6;
    const int lane = tid & 63;
    const int quad = lane >> 4;
    const int n    = lane & 15;
    const int wm   = w >> 1, wn = w & 1;

    // DMA chunk coords: ci = (w*2+c)*64 + lane; row = ci>>2; col8 = (ci&3)*8
    const int ci0 = (w * 2 + 0) * 64 + lane;
    const int ci1 = (w * 2 + 1) * 64 + lane;
    const int r0c = ci0 >> 2, c0c = (ci0 & 3) * 8;
    const int r1c = ci1 >> 2, c1c = (ci1 & 3) * 8;
    _Float16* ldsA0 = &Ah[(w * 2 + 0) * 512];
    _Float16* ldsA1 = &Ah[(w * 2 + 1) * 512];
    _Float16* ldsB0 = &Bh[(w * 2 + 0) * 512];
    _Float16* ldsB1 = &Bh[(w * 2 + 1) * 512];

    f32x4 acc[4][4] = {};

    for (int k0 = 0; k0 < DD; k0 += 32) {
        __syncthreads();   // prior frag reads done
        GLDS16(&xh[(size_t)(m0 + r0c) * DD + k0 + c0c], ldsA0);
        GLDS16(&xh[(size_t)(m0 + r1c) * DD + k0 + c1c], ldsA1);
        GLDS16(&Wp[(size_t)(n0 + r0c) * DD + k0 + c0c], ldsB0);
        GLDS16(&Wp[(size_t)(n0 + r1c) * DD + k0 + c1c], ldsB1);
        __syncthreads();   // compiler drains vmcnt before barrier
        half8 af[4], bf[4];
        #pragma unroll
        for (int mi = 0; mi < 4; ++mi)
            af[mi] = *(const half8*)&Ah[(wm*64 + mi*16 + n) * 32 + quad*8];
        #pragma unroll
        for (int ni = 0; ni < 4; ++ni)
            bf[ni] = *(const half8*)&Bh[(wn*64 + ni*16 + n) * 32 + quad*8];
        #pragma unroll
        for (int mi = 0; mi < 4; ++mi)
            #pragma unroll
            for (int ni = 0; ni < 4; ++ni)
                acc[mi][ni] = __builtin_amdgcn_mfma_f32_16x16x32_f16(
                    af[mi], bf[ni], acc[mi][ni], 0, 0, 0);
    }

    #pragma unroll
    for (int mi = 0; mi < 4; ++mi) {
        #pragma unroll
        for (int ni = 0; ni < 4; ++ni) {
            const int col = n0 + wn*64 + ni*16 + n;   // 0..511
            const int h   = col >> 6;
            const int dk  = col & 63;
            const float bias = bp[col];
            const int gbase = m0 + wm*64 + mi*16 + quad*4;
            const int bidx  = gbase >> 10;
            const int sr    = gbase & (SS - 1);
            if (!is_v) {
                #pragma unroll
                for (int reg = 0; reg < 4; ++reg)
                    q_ws[((size_t)(bidx * HH + h) * SS + sr + reg) * DKK + dk] =
                        (_Float16)(acc[mi][ni][reg] + bias);
            } else {
                _Float16 h4[4];
                #pragma unroll
                for (int reg = 0; reg < 4; ++reg)
                    h4[reg] = (_Float16)(acc[mi][ni][reg] + bias);
                *(uint2*)&vt_ws[((size_t)(bidx * HH + h) * DKK + dk) * SS + sr] =
                    *(uint2*)h4;
            }
        }
    }
}

// ---------------------------------------------------------------------------
// GEMM #2, m97-style: out = attn_h @ Wo^T + bo (A fp16 from attn, out fp32)
// ---------------------------------------------------------------------------
__global__ __launch_bounds__(256) void gemm_out(
    const _Float16* __restrict__ A,
    const _Float16* __restrict__ woh, const float* __restrict__ bo,
    float* __restrict__ out)
{
    __shared__ __align__(16) _Float16 Ah[128 * 32];
    __shared__ __align__(16) _Float16 Bh[128 * 32];

    const int m0 = blockIdx.x * 128;
    const int n0 = blockIdx.y * 128;

    const int tid  = threadIdx.x;
    const int w    = tid >> 6;
    const int lane = tid & 63;
    const int quad = lane >> 4;
    const int n    = lane & 15;
    const int wm   = w >> 1, wn = w & 1;

    const int ci0 = (w * 2 + 0) * 64 + lane;
    const int ci1 = (w * 2 + 1) * 64 + lane;
    const int r0c = ci0 >> 2, c0c = (ci0 & 3) * 8;
    const int r1c = ci1 >> 2, c1c = (ci1 & 3) * 8;
    _Float16* ldsA0 = &Ah[(w * 2 + 0) * 512];
    _Float16* ldsA1 = &Ah[(w * 2 + 1) * 512];
    _Float16* ldsB0 = &Bh[(w * 2 + 0) * 512];
    _Float16* ldsB1 = &Bh[(w * 2 + 1) * 512];

    f32x4 acc[4][4] = {};

    for (int k0 = 0; k0 < DD; k0 += 32) {
        __syncthreads();
        GLDS16(&A[(size_t)(m0 + r0c) * DD + k0 + c0c], ldsA0);
        GLDS16(&A[(size_t)(m0 + r1c) * DD + k0 + c1c], ldsA1);
        GLDS16(&woh[(size_t)(n0 + r0c) * DD + k0 + c0c], ldsB0);
        GLDS16(&woh[(size_t)(n0 + r1c) * DD + k0 + c1c], ldsB1);
        __syncthreads();
        half8 af[4], bf[4];
        #pragma unroll
        for (int mi = 0; mi < 4; ++mi)
            af[mi] = *(const half8*)&Ah[(wm*64 + mi*16 + n) * 32 + quad*8];
        #pragma unroll
        for (int ni = 0; ni < 4; ++ni)
            bf[ni] = *(const half8*)&Bh[(wn*64 + ni*16 + n) * 32 + quad*8];
        #pragma unroll
        for (int mi = 0; mi < 4; ++mi)
            #pragma unroll
            for (int ni = 0; ni < 4; ++ni)
                acc[mi][ni] = __builtin_amdgcn_mfma_f32_16x16x32_f16(
                    af[mi], bf[ni], acc[mi][ni], 0, 0, 0);
    }

    #pragma unroll
    for (int mi = 0; mi < 4; ++mi) {
        #pragma unroll
        for (int ni = 0; ni < 4; ++ni) {
            const int col  = n0 + wn*64 + ni*16 + n;
            const float bias = bo[col];
            const int gbase = m0 + wm*64 + mi*16 + quad*4;
            #pragma unroll
            for (int reg = 0; reg < 4; ++reg)
                out[(size_t)(gbase + reg) * DD + col] = acc[mi][ni][reg] + bias;
        }
    }
}

// ---------------------------------------------------------------------------
// MFMA attention — EXACT R6 body (227 µs, 3x reproduced); only change:
// output stored fp16 (gemm_out staged to fp16 anyway — same rounding).
// Known-toxic variants (do not retry): 16-wave PV + o_red (R7); utT fold
// into post-barrier pull + tmax (R10); 8-wave blocks (R13).
// ---------------------------------------------------------------------------
__global__ __launch_bounds__(1024) void attn_mfma(
    const _Float16* __restrict__ q,   // [B,H,S,DK] fp16 (K = Q)
    const _Float16* __restrict__ vt,  // [B,H,DK,S] fp16 (V transposed)
    const float* __restrict__ utT,    // [B,S,S]
    const float* __restrict__ gammas, // [H]
    _Float16* __restrict__ attn)      // [B,S,H,DK] fp16
{
    __shared__ __align__(16) float    s_lds[2 * 16 * SSTR];  // 32896 B
    __shared__ __align__(16) _Float16 q_lds[16 * QSTR];      // 2816 B
    _Float16* p_lds = (_Float16*)s_lds;  // phase 3: 2 x 16 x PSTR halves

    const int tid  = threadIdx.x;
    const int w    = tid >> 6;
    const int lane = tid & 63;
    const int quad = lane >> 4;
    const int n    = lane & 15;
    const int bh   = blockIdx.y;
    const int b    = bh >> 3;
    const int h    = bh & 7;
    const int r0   = blockIdx.x * 16;

    const _Float16* __restrict__ kq  = q  + (size_t)bh * SS * DKK;
    const _Float16* __restrict__ vtp = vt + (size_t)bh * DKK * SS;

    const int nchunk = (r0 + 16 + 255) >> 8;   // 1..4, block-uniform
    const int nt     = nchunk * 4;

    if (tid < 256) {
        const int row = tid >> 4;
        const int c   = tid & 15;
        *(uint2*)&q_lds[row * QSTR + c * 4] =
            *(const uint2*)&kq[(size_t)(r0 + row) * DKK + c * 4];
    }
    __syncthreads();

    float sreg[16];
    #pragma unroll
    for (int t2 = 0; t2 < 16; ++t2) sreg[t2] = NEGF;

    // ---- Phase 1 ----
    #pragma unroll
    for (int c0 = 0; c0 < 4; ++c0) {
        if (c0 < nchunk) {
            const int j0  = c0 * 256;
            const int buf = (c0 & 1) * 16 * SSTR;
            const int jbase = j0 + w * 16;
            if (jbase <= r0 + 15) {
                const _Float16* krow = &kq[(size_t)(jbase + n) * DKK];
                half8 b0 = *(const half8*)&krow[quad * 8];
                half8 b1 = *(const half8*)&krow[32 + quad * 8];
                half8 a0 = *(const half8*)&q_lds[n * QSTR + quad * 8];
                half8 a1 = *(const half8*)&q_lds[n * QSTR + 32 + quad * 8];
                f32x4 d = {0.f, 0.f, 0.f, 0.f};
                d = __builtin_amdgcn_mfma_f32_16x16x32_f16(a0, b0, d, 0, 0, 0);
                d = __builtin_amdgcn_mfma_f32_16x16x32_f16(a1, b1, d, 0, 0, 0);
                const int j = jbase + n;
                #pragma unroll
                for (int reg = 0; reg < 4; ++reg) {
                    const int i = r0 + quad * 4 + reg;
                    float val = NEGF;
                    if (j <= i)
                        val = d[reg] * 0.125f * utT[((size_t)b * SS + i) * SS + j];
                    s_lds[buf + (quad * 4 + reg) * SSTR + w * 16 + n] = val;
                }
            } else {
                #pragma unroll
                for (int reg = 0; reg < 4; ++reg)
                    s_lds[buf + (quad * 4 + reg) * SSTR + w * 16 + n] = NEGF;
            }
            __syncthreads();
            #pragma unroll
            for (int ttl = 0; ttl < 4; ++ttl)
                sreg[c0 * 4 + ttl] = s_lds[buf + w * SSTR + ttl * 64 + lane];
        }
    }

    // ---- Phase 2 ----
    const int i_row = r0 + w;

    float m1 = NEGF;
    #pragma unroll
    for (int t2 = 0; t2 < 16; ++t2) if (t2 < nt) m1 = fmaxf(m1, sreg[t2]);
    #pragma unroll
    for (int o = 32; o >= 1; o >>= 1) m1 = fmaxf(m1, __shfl_xor(m1, o));

    float ee[16];
    float z1 = 0.f;
    #pragma unroll
    for (int t2 = 0; t2 < 16; ++t2) {
        float e = 0.f;
        if (t2 < nt) {
            const int j = t2 * 64 + lane;
            if (j <= i_row) e = __expf(sreg[t2] - m1);
        }
        ee[t2] = e;
        z1 += e;
    }
    #pragma unroll
    for (int o = 32; o >= 1; o >>= 1) z1 += __shfl_xor(z1, o);
    const float inv_z1 = 1.0f / z1;

    const float g     = gammas[h];
    const float gamma = -log1pf(__expf(g));   // -softplus

    float carry = 0.f;
    float m2 = NEGF;
    #pragma unroll
    for (int t2 = 0; t2 < 16; ++t2) {
        if (t2 < nt) {
            float xv = ee[t2];
            #pragma unroll
            for (int o = 1; o < 64; o <<= 1) {
                float y = __shfl_up(xv, (unsigned)o);
                if (lane >= o) xv += y;
            }
            const float tile_tot = __shfl(xv, 63);
            const float csum = (carry + xv) * inv_z1;
            carry += tile_tot;

            const int j = t2 * 64 + lane;
            const float pe = (float)(i_row - j);
            const float dd = fmaxf((1.0f - csum) * pe, 0.0f);
            float te = __expf(sqrtf(dd) * gamma);
            te = fminf(fmaxf(te, 1e-5f), 1e5f);
            const float nsv = (j <= i_row) ? sreg[t2] * te : NEGF;
            ee[t2] = nsv;
            m2 = fmaxf(m2, nsv);
        }
    }
    #pragma unroll
    for (int o = 32; o >= 1; o >>= 1) m2 = fmaxf(m2, __shfl_xor(m2, o));

    float z2 = 0.f;
    #pragma unroll
    for (int t2 = 0; t2 < 16; ++t2) {
        if (t2 < nt) {
            ee[t2] = __expf(ee[t2] - m2);
            z2 += ee[t2];
        }
    }
    #pragma unroll
    for (int o = 32; o >= 1; o >>= 1) z2 += __shfl_xor(z2, o);
    const float inv_z2 = 1.0f / z2;
    #pragma unroll
    for (int t2 = 0; t2 < 16; ++t2) if (t2 < nt) ee[t2] *= inv_z2;

    __syncthreads();

    // ---- Phase 3 ----
    f32x4 oacc = {0.f, 0.f, 0.f, 0.f};
    #pragma unroll
    for (int c0 = 0; c0 < 4; ++c0) {
        if (c0 < nchunk) {
            const int j0 = c0 * 256;
            const int pb = (c0 & 1) * 16 * PSTR;
            #pragma unroll
            for (int ttl = 0; ttl < 4; ++ttl)
                p_lds[pb + w * PSTR + ttl * 64 + lane] = (_Float16)ee[c0 * 4 + ttl];
            __syncthreads();
            if (w < 4) {
                int nkt = (r0 + 16 - j0 + 31) >> 5;
                nkt = (nkt > 8) ? 8 : nkt;
                const _Float16* vrow = &vtp[(size_t)(w * 16 + n) * SS + j0];
                for (int kt = 0; kt < nkt; ++kt) {
                    half8 a  = *(const half8*)&p_lds[pb + n * PSTR + kt * 32 + quad * 8];
                    half8 bb = *(const half8*)&vrow[kt * 32 + quad * 8];
                    oacc = __builtin_amdgcn_mfma_f32_16x16x32_f16(a, bb, oacc, 0, 0, 0);
                }
            }
        }
    }

    if (w < 4) {
        #pragma unroll
        for (int reg = 0; reg < 4; ++reg) {
            const int i = r0 + quad * 4 + reg;
            attn[(((size_t)b * SS + i) * HH + h) * DKK + w * 16 + n] =
                (_Float16)oacc[reg];
        }
    }
}

// ---------------------------------------------------------------------------
extern "C" void kernel_launch(void* const* d_in, const int* in_sizes, int n_in,
                              void* d_out, int out_size, void* d_ws, size_t ws_size,
                              hipStream_t stream) {
    const float* x      = (const float*)d_in[0];
    const float* utT    = (const float*)d_in[1];
    const float* Wk     = (const float*)d_in[2];
    const float* bk     = (const float*)d_in[3];
    const float* Wv     = (const float*)d_in[4];
    const float* bv     = (const float*)d_in[5];
    const float* Wo     = (const float*)d_in[6];
    const float* bo     = (const float*)d_in[7];
    const float* gammas = (const float*)d_in[8];
    float* out = (float*)d_out;

    const size_t NX  = (size_t)NB * SS * DD;   // 4,194,304
    const size_t NW  = (size_t)DD * DD;        // 262,144
    const size_t per = NX;

    _Float16* p      = (_Float16*)d_ws;
    _Float16* xh     = p;  p += NX;
    _Float16* wkh    = p;  p += NW;
    _Float16* wvh    = p;  p += NW;
    _Float16* woh    = p;  p += NW;
    _Float16* q_ws   = p;  p += per;
    _Float16* vt_ws  = p;  p += per;
    _Float16* attn_h = p;  p += per;           // total ~33.5 MB

    const int cvt_blocks = (int)((NX + 3 * NW) / 8 / 256);  // 2432
    cvt_fp16<<<cvt_blocks, dim3(256), 0, stream>>>(
        x, xh, Wk, wkh, Wv, wvh, Wo, woh);

    dim3 g1(64, 8);    // 128x128 tiles, M=8192, N=1024 (q||v)
    gemm_qv<<<g1, dim3(256), 0, stream>>>(xh, wkh, bk, wvh, bv, q_ws, vt_ws);

    dim3 g2(SS / 16, NB * HH);
    attn_mfma<<<g2, dim3(1024), 0, stream>>>(q_ws, vt_ws, utT, gammas, attn_h);

    dim3 g3(64, 4);    // 128x128 tiles, M=8192, N=512
    gemm_out<<<g3, dim3(256), 0, stream>>>(attn_h, woh, bo, out);
}